// Round 1
// baseline (52.546 us; speedup 1.0000x reference)
//
#include <hip/hip_runtime.h>

// Delay-logistic DDE, forward Euler, d independent scalar components.
// x_{i+1} = x_i * m_i,  m_i = (1+a) - a*th1*y_i,  a = dt*th0,
// y_i = x_{i-100} (constant history x_0 for i < 100).
// Output: out[j*(N+1) + t] = x_t for component j  (traj.T, row-major [d, N+1]).

constexpr int NT   = 1000;          // N steps (harness uses setup_inputs: N=1000)
constexpr int NTAU = 100;           // steps per delay interval
constexpr int NGRP = NT / NTAU;     // 10 groups of 100 steps
constexpr int NP1  = NT + 1;        // 1001 columns per row
constexpr int CPB  = 64;            // components per block == block size (1 wave)
constexpr int LDSS = NTAU + 1;      // 101: stride 101 ≡ 5 (mod 32), conflict-free

__global__ __launch_bounds__(CPB, 1)
void ndde_kernel(const float* __restrict__ x0,
                 const float* __restrict__ tau,
                 const float* __restrict__ params,
                 float* __restrict__ out)
{
    __shared__ float lds[CPB][LDSS];
    const int tid = threadIdx.x;
    const long long jbase = (long long)blockIdx.x * CPB;
    const int j = (int)jbase + tid;

    const float dt = 0.01f * tau[0];
    const float a  = dt * params[0];        // dt * theta0
    const float q  = -(a * params[1]);      // -dt*theta0*theta1
    const float p  = 1.0f + a;

    float x = x0[j];
    // h[k] at start of group g holds x_{100*(g-1)+k}; for g=0 the constant
    // history x(t<=0) = x_0.
    float h[NTAU];
#pragma unroll
    for (int k = 0; k < NTAU; ++k) h[k] = x;

    for (int g = 0; g < NGRP; ++g) {
        // --- compute 100 steps; dependent chain is just x *= m (m off-chain) ---
#pragma unroll
        for (int k = 0; k < NTAU; ++k) {
            const float y = h[k];           // x_{i-100}
            const float m = fmaf(q, y, p);  // (1+a) - a*th1*y
            h[k] = x;                       // save x_{100g+k} for group g+1 and output
            x *= m;
        }
        // h[k] now holds x_{100g+k}: exactly output columns t = 100g .. 100g+99.

        // --- stage to LDS (lanes write same k, stride-101 rows: conflict-free) ---
#pragma unroll
        for (int k = 0; k < NTAU; ++k) lds[tid][k] = h[k];
        __syncthreads();

        // --- transpose drain: lane index runs along the TIME axis (coalesced) ---
        const long long t0 = (long long)g * NTAU;
        for (int r = 0; r < CPB; ++r) {
            float* rowp = out + (jbase + r) * NP1 + t0;
            rowp[tid] = lds[r][tid];                       // t = t0 + 0..63
            if (tid < NTAU - 64)
                rowp[64 + tid] = lds[r][64 + tid];         // t = t0 + 64..99
        }
        __syncthreads();   // protect LDS before next group's writes
    }
    // final column t = N
    out[(long long)j * NP1 + NT] = x;
}

extern "C" void kernel_launch(void* const* d_in, const int* in_sizes, int n_in,
                              void* d_out, int out_size, void* d_ws, size_t ws_size,
                              hipStream_t stream) {
    const float* x0     = (const float*)d_in[0];
    const float* tau    = (const float*)d_in[1];
    const float* params = (const float*)d_in[2];
    float* out = (float*)d_out;
    const int d = in_sizes[0];              // 32768
    const int nblocks = d / CPB;            // 512
    ndde_kernel<<<nblocks, CPB, 0, stream>>>(x0, tau, params, out);
}

// Round 2
// 39.460 us; speedup vs baseline: 1.3316x; 1.3316x over previous
//
#include <hip/hip_runtime.h>

// Delay-logistic DDE, forward Euler, d independent scalar components.
// x_{i+1} = x_i * m_i,  m_i = (1+a) - a*th1*y_i,  a = dt*th0,
// y_i = x_{i-100} (constant history x_0 for i < 100).
// Output: out[j*(N+1) + t] = x_t  (row-major [d, N+1]).
//
// Parallelization: block = (64-component chunk) x (time-group g of 100 steps).
// Each block recomputes groups 0..g from x_0 (cheap: ~3 VALU/step, longest
// serial chain 1000 fma-latency ~2us) and writes only group g's columns via
// one LDS transpose + one coalesced drain. 5120 independent blocks -> stores
// stream without per-group vmcnt(0)+barrier serialization (round-1 limiter).

constexpr int NT   = 1000;          // N steps (setup_inputs: N=1000)
constexpr int NTAU = 100;           // steps per delay interval
constexpr int NGRP = NT / NTAU;     // 10 groups
constexpr int NP1  = NT + 1;        // 1001 columns per row
constexpr int CPB  = 64;            // components per block == block size (1 wave)
constexpr int LDSS = NTAU + 1;      // 101: stride ≡ 5 (mod 32) -> conflict-free

__global__ __launch_bounds__(CPB)
void ndde_kernel(const float* __restrict__ x0,
                 const float* __restrict__ tau,
                 const float* __restrict__ params,
                 float* __restrict__ out)
{
    __shared__ float lds[CPB][LDSS];
    const int tid = threadIdx.x;
    // g = NGRP-1 - blockIdx.y: longest-recompute blocks dispatch FIRST.
    const int g = (NGRP - 1) - (int)blockIdx.y;
    const long long jbase = (long long)blockIdx.x * CPB;
    const int j = (int)jbase + tid;

    const float dt = 0.01f * tau[0];
    const float a  = dt * params[0];        // dt * theta0
    const float q  = -(a * params[1]);      // -dt*theta0*theta1
    const float p  = 1.0f + a;

    float x = x0[j];
    // h[k] at start of group gg holds x_{100*(gg-1)+k}; constant history for gg=0.
    float h[NTAU];
#pragma unroll
    for (int k = 0; k < NTAU; ++k) h[k] = x;

    // Recompute groups 0..g; after iteration gg, h[k] = x_{100*gg+k}.
    for (int gg = 0; gg <= g; ++gg) {
#pragma unroll
        for (int k = 0; k < NTAU; ++k) {
            const float y = h[k];           // x_{i-100}
            const float m = fmaf(q, y, p);  // (1+a) - a*th1*y
            h[k] = x;                       // becomes x_{100*gg+k}
            x *= m;
        }
    }
    // h[k] = x_{100g+k}: output columns t = 100g .. 100g+99.

    // Stage to LDS (lanes along comps, stride-101 rows: 2-way = free).
#pragma unroll
    for (int k = 0; k < NTAU; ++k) lds[tid][k] = h[k];
    __syncthreads();

    // Transpose drain: lane index runs along TIME (coalesced 256B + 144B).
    const long long t0 = (long long)g * NTAU;
#pragma unroll 4
    for (int r = 0; r < CPB; ++r) {
        float* rowp = out + (jbase + r) * NP1 + t0;
        rowp[tid] = lds[r][tid];                       // t = t0 + 0..63
        if (tid < NTAU - 64)
            rowp[64 + tid] = lds[r][64 + tid];         // t = t0 + 64..99
    }

    // Final column t = N written by the g = NGRP-1 blocks (x = x_1000 here).
    if (g == NGRP - 1)
        out[(long long)j * NP1 + NT] = x;
}

extern "C" void kernel_launch(void* const* d_in, const int* in_sizes, int n_in,
                              void* d_out, int out_size, void* d_ws, size_t ws_size,
                              hipStream_t stream) {
    const float* x0     = (const float*)d_in[0];
    const float* tau    = (const float*)d_in[1];
    const float* params = (const float*)d_in[2];
    float* out = (float*)d_out;
    const int d = in_sizes[0];              // 32768
    const int chunks = d / CPB;             // 512
    dim3 grid(chunks, NGRP);
    ndde_kernel<<<grid, CPB, 0, stream>>>(x0, tau, params, out);
}